// Round 6
// baseline (4139.367 us; speedup 1.0000x reference)
//
#include <hip/hip_runtime.h>
#include <hip/hip_fp16.h>
#include <hip/hip_cooperative_groups.h>

namespace cg = cooperative_groups;

// Sinkhorn-Knopp, factorized M = diag(r) * exp(H) * diag(c).
// V6: cooperative kernel with E ON-CHIP across all 20 iterations.
// Per wave (16 rows): 6 rows in VGPRs, 2 rows in LDS, 8 rows streamed from
// the (L2/L3-hot, 56 MB/iter) global E. Per-iteration global traffic is
// only the 2 MB column-partial exchange + stream reads. c and r persist in
// LDS. 20 grid.sync()s replace 21 kernel launches.
// Addresses all three k_mega (round-1) pathologies: no E re-stream, no
// forced 64-VGPR cap, nothing dirty at the fence except 2 MB partials.

constexpr int NB    = 64;
constexpr int N     = 1024;
constexpr int NITER = 20;
constexpr float EPS = 1e-8f;

// ---- legacy (V5) path constants ----
constexpr int SLABS = 16;
constexpr int TPB   = 512;
constexpr int WAVES = TPB / 64;
constexpr int RPB   = N / SLABS;
constexpr int RPW   = RPB / WAVES;

// ---- cooperative path constants ----
constexpr int CSLAB = 8;             // blocks per batch
constexpr int CBLK  = NB * CSLAB;    // 512 blocks = 2/CU
constexpr int CRPW  = 16;            // rows per wave
constexpr int RROWS = 6;             // rows in registers / wave
constexpr int LROWS = 2;             // rows in LDS / wave
constexpr int SROWS = CRPW - RROWS - LROWS;  // 8 streamed rows / wave

template <typename ET> struct VT;
template <> struct VT<__half> { static constexpr int CPL = 8, STEPS = 2; };
template <> struct VT<float>  { static constexpr int CPL = 4, STEPS = 4; };

__device__ inline void load16B(const __half* p, float* f) {
  uint4 u = *reinterpret_cast<const uint4*>(p);
  float2 t;
  t = __half22float2(*reinterpret_cast<__half2*>(&u.x)); f[0] = t.x; f[1] = t.y;
  t = __half22float2(*reinterpret_cast<__half2*>(&u.y)); f[2] = t.x; f[3] = t.y;
  t = __half22float2(*reinterpret_cast<__half2*>(&u.z)); f[4] = t.x; f[5] = t.y;
  t = __half22float2(*reinterpret_cast<__half2*>(&u.w)); f[6] = t.x; f[7] = t.y;
}
__device__ inline void load16B(const float* p, float* f) {
  float4 v = *reinterpret_cast<const float4*>(p);
  f[0] = v.x; f[1] = v.y; f[2] = v.z; f[3] = v.w;
}

__device__ __forceinline__ void unpack8(uint4 u, float* f) {
  float2 t;
  t = __half22float2(*reinterpret_cast<__half2*>(&u.x)); f[0] = t.x; f[1] = t.y;
  t = __half22float2(*reinterpret_cast<__half2*>(&u.y)); f[2] = t.x; f[3] = t.y;
  t = __half22float2(*reinterpret_cast<__half2*>(&u.z)); f[4] = t.x; f[5] = t.y;
  t = __half22float2(*reinterpret_cast<__half2*>(&u.w)); f[6] = t.x; f[7] = t.y;
}

// pack 8 floats -> fp16x8; overwrite inputs with the ROUNDED values
__device__ __forceinline__ uint4 pack8(float* e) {
  __half2 p0 = __floats2half2_rn(e[0], e[1]);
  __half2 p1 = __floats2half2_rn(e[2], e[3]);
  __half2 p2 = __floats2half2_rn(e[4], e[5]);
  __half2 p3 = __floats2half2_rn(e[6], e[7]);
  uint4 u;
  u.x = *reinterpret_cast<unsigned*>(&p0);
  u.y = *reinterpret_cast<unsigned*>(&p1);
  u.z = *reinterpret_cast<unsigned*>(&p2);
  u.w = *reinterpret_cast<unsigned*>(&p3);
  float2 t;
  t = __half22float2(p0); e[0] = t.x; e[1] = t.y;
  t = __half22float2(p1); e[2] = t.x; e[3] = t.y;
  t = __half22float2(p2); e[4] = t.x; e[5] = t.y;
  t = __half22float2(p3); e[6] = t.x; e[7] = t.y;
  return u;
}

// exp of one H row into e[16] (rounded-to-fp16) + packed u[2]
__device__ __forceinline__ void exp_row(const float* Hrow, int l,
                                        float (&e)[16], uint4 (&u)[2]) {
#pragma unroll
  for (int q = 0; q < 2; ++q) {
    float4 h0 = *reinterpret_cast<const float4*>(Hrow + q * 512 + l * 8);
    float4 h1 = *reinterpret_cast<const float4*>(Hrow + q * 512 + l * 8 + 4);
    e[q * 8 + 0] = __expf(h0.x); e[q * 8 + 1] = __expf(h0.y);
    e[q * 8 + 2] = __expf(h0.z); e[q * 8 + 3] = __expf(h0.w);
    e[q * 8 + 4] = __expf(h1.x); e[q * 8 + 5] = __expf(h1.y);
    e[q * 8 + 6] = __expf(h1.z); e[q * 8 + 7] = __expf(h1.w);
    u[q] = pack8(&e[q * 8]);
  }
}

// row sum with c, butterfly reduce, r update (identical math to V5)
__device__ __forceinline__ float row_rn(const float (&ev)[16],
                                        const float (&creg)[16], float ro) {
  float a0 = 0.f, a1 = 0.f, a2 = 0.f, a3 = 0.f;
#pragma unroll
  for (int k = 0; k < 4; ++k) {
    a0 = fmaf(ev[k],      creg[k],      a0);
    a1 = fmaf(ev[k + 4],  creg[k + 4],  a1);
    a2 = fmaf(ev[k + 8],  creg[k + 8],  a2);
    a3 = fmaf(ev[k + 12], creg[k + 12], a3);
  }
  float acc = (a0 + a1) + (a2 + a3);
#pragma unroll
  for (int off = 32; off > 0; off >>= 1) acc += __shfl_xor(acc, off, 64);
  return ro / (ro * acc + EPS);
}

__device__ __forceinline__ void write_m(float* M, size_t row, int l,
                                        const float (&ev)[16], float rn,
                                        const float (&creg)[16]) {
  float* Mrow = M + row * (size_t)N;
#pragma unroll
  for (int q = 0; q < 2; ++q)
#pragma unroll
    for (int v = 0; v < 2; ++v) {
      int k = q * 8 + v * 4;
      *reinterpret_cast<float4*>(Mrow + q * 512 + l * 8 + v * 4) =
          make_float4(ev[k] * rn * creg[k], ev[k + 1] * rn * creg[k + 1],
                      ev[k + 2] * rn * creg[k + 2], ev[k + 3] * rn * creg[k + 3]);
    }
}

// two-phase 8-wave merge of per-lane column partials through red[4][N],
// then per-thread final sum -> out[j]
__device__ __forceinline__ void merge_store(const float (&ca)[16],
                                            float (*red)[N], int tid, int w,
                                            int l, float* out) {
  if (w >= 4) {
#pragma unroll
    for (int q = 0; q < 2; ++q)
#pragma unroll
      for (int v = 0; v < 2; ++v) {
        int k = q * 8 + v * 4;
        *reinterpret_cast<float4*>(&red[w - 4][q * 512 + l * 8 + v * 4]) =
            make_float4(ca[k], ca[k + 1], ca[k + 2], ca[k + 3]);
      }
  }
  __syncthreads();
  if (w < 4) {
#pragma unroll
    for (int q = 0; q < 2; ++q)
#pragma unroll
      for (int v = 0; v < 2; ++v) {
        int k = q * 8 + v * 4;
        float4 p = *reinterpret_cast<float4*>(&red[w][q * 512 + l * 8 + v * 4]);
        p.x += ca[k]; p.y += ca[k + 1]; p.z += ca[k + 2]; p.w += ca[k + 3];
        *reinterpret_cast<float4*>(&red[w][q * 512 + l * 8 + v * 4]) = p;
      }
  }
  __syncthreads();
  for (int j = tid; j < N; j += 512) {
    out[j] = (red[0][j] + red[1][j]) + (red[2][j] + red[3][j]);
  }
}

// ---------------------------------------------------------------------------
// Cooperative resident kernel: init + 20 iterations, E on-chip.
// ---------------------------------------------------------------------------
__global__ __launch_bounds__(512, 4) void k_res(
    const float* __restrict__ H, __half* __restrict__ E,
    float* __restrict__ Ap0, float* __restrict__ Ap1, float* __restrict__ M) {
  __shared__ float cs[N];                 // 4 KB   (c, persistent)
  __shared__ float red[4][N];             // 16 KB  (merge scratch)
  __shared__ float rls[128];              // 0.5 KB (r, persistent)
  __shared__ __half EL[8][LROWS][N];      // 32 KB  (LDS-resident E rows)

  const int b = blockIdx.x / CSLAB, s = blockIdx.x % CSLAB;
  const int tid = threadIdx.x, w = tid >> 6, l = tid & 63;
  const size_t brow = (size_t)b * N;
  const int i0 = s * 128 + w * CRPW;

  uint4 er[RROWS][2];  // register-resident E rows (static indexing only)

  // ---- init: E = exp(H) into regs/LDS/global, iter-0 column partials ----
  {
    float ca[16];
#pragma unroll
    for (int k = 0; k < 16; ++k) ca[k] = 0.f;
    if (tid < 128) rls[tid] = 1.f;
    for (int j = tid; j < N; j += 512) cs[j] = 1.f;

#pragma unroll
    for (int t = 0; t < RROWS; ++t) {
      float e[16]; uint4 u[2];
      exp_row(H + (brow + i0 + t) * N, l, e, u);
      er[t][0] = u[0]; er[t][1] = u[1];
#pragma unroll
      for (int k = 0; k < 16; ++k) ca[k] += e[k];
    }
#pragma unroll
    for (int t = 0; t < LROWS; ++t) {
      float e[16]; uint4 u[2];
      exp_row(H + (brow + i0 + RROWS + t) * N, l, e, u);
      reinterpret_cast<uint4*>(&EL[w][t][0])[l] = u[0];
      reinterpret_cast<uint4*>(&EL[w][t][512])[l] = u[1];
#pragma unroll
      for (int k = 0; k < 16; ++k) ca[k] += e[k];
    }
#pragma unroll 2
    for (int t = 0; t < SROWS; ++t) {
      float e[16]; uint4 u[2];
      size_t row = brow + i0 + RROWS + LROWS + t;
      exp_row(H + row * N, l, e, u);
      __half* Erow = E + row * (size_t)N;
      *reinterpret_cast<uint4*>(Erow + l * 8) = u[0];
      *reinterpret_cast<uint4*>(Erow + 512 + l * 8) = u[1];
#pragma unroll
      for (int k = 0; k < 16; ++k) ca[k] += e[k];
    }
    merge_store(ca, red, tid, w, l, Ap0 + ((size_t)b * CSLAB + s) * N);
  }

  cg::grid_group grid = cg::this_grid();
  __threadfence();
  grid.sync();

  // ---- 20 iterations ----
  for (int it = 0; it < NITER; ++it) {
    const bool last = (it == NITER - 1);
    const float* AIn = (it & 1) ? Ap1 : Ap0;
    float* AOut = (it & 1) ? Ap0 : Ap1;

    // phase a: column-scale update (cs RMW is same-thread each iter)
    for (int j = tid; j < N; j += 512) {
      float A = 0.f;
#pragma unroll
      for (int p = 0; p < CSLAB; ++p)
        A += AIn[((size_t)b * CSLAB + p) * N + j];
      float cv = cs[j];
      cs[j] = cv / (cv * A + EPS);
    }
    __syncthreads();

    float creg[16];
#pragma unroll
    for (int q = 0; q < 2; ++q)
#pragma unroll
      for (int m = 0; m < 8; ++m) creg[q * 8 + m] = cs[q * 512 + l * 8 + m];

    float ca[16];
#pragma unroll
    for (int k = 0; k < 16; ++k) ca[k] = 0.f;

    // register rows
#pragma unroll
    for (int t = 0; t < RROWS; ++t) {
      float ev[16];
      unpack8(er[t][0], ev); unpack8(er[t][1], ev + 8);
      float rn = row_rn(ev, creg, rls[w * CRPW + t]);
      if (last) {
        write_m(M, brow + i0 + t, l, ev, rn, creg);
      } else {
        if (l == 0) rls[w * CRPW + t] = rn;
#pragma unroll
        for (int k = 0; k < 16; ++k) ca[k] = fmaf(ev[k], rn, ca[k]);
      }
    }
    // LDS rows
#pragma unroll
    for (int t = 0; t < LROWS; ++t) {
      float ev[16];
      uint4 u0 = reinterpret_cast<const uint4*>(&EL[w][t][0])[l];
      uint4 u1 = reinterpret_cast<const uint4*>(&EL[w][t][512])[l];
      unpack8(u0, ev); unpack8(u1, ev + 8);
      int tt = RROWS + t;
      float rn = row_rn(ev, creg, rls[w * CRPW + tt]);
      if (last) {
        write_m(M, brow + i0 + tt, l, ev, rn, creg);
      } else {
        if (l == 0) rls[w * CRPW + tt] = rn;
#pragma unroll
        for (int k = 0; k < 16; ++k) ca[k] = fmaf(ev[k], rn, ca[k]);
      }
    }
    // streamed rows (L2/L3-hot; only vmem in the loop)
#pragma unroll 2
    for (int t = 0; t < SROWS; ++t) {
      int tt = RROWS + LROWS + t;
      const __half* Erow = E + (brow + i0 + tt) * (size_t)N;
      float ev[16];
      uint4 u0 = *reinterpret_cast<const uint4*>(Erow + l * 8);
      uint4 u1 = *reinterpret_cast<const uint4*>(Erow + 512 + l * 8);
      unpack8(u0, ev); unpack8(u1, ev + 8);
      float rn = row_rn(ev, creg, rls[w * CRPW + tt]);
      if (last) {
        write_m(M, brow + i0 + tt, l, ev, rn, creg);
      } else {
        if (l == 0) rls[w * CRPW + tt] = rn;
#pragma unroll
        for (int k = 0; k < 16; ++k) ca[k] = fmaf(ev[k], rn, ca[k]);
      }
    }

    if (!last) {
      merge_store(ca, red, tid, w, l, AOut + ((size_t)b * CSLAB + s) * N);
      __threadfence();
      grid.sync();
    }
  }
}

// ---------------------------------------------------------------------------
// Legacy multi-launch path (V5, proven 1034 us): coop-failure / fp32 fallback.
// ---------------------------------------------------------------------------
template <typename ET>
__global__ __launch_bounds__(TPB, 4) void k_init(const float* __restrict__ H,
                                                 ET* __restrict__ E,
                                                 float* __restrict__ Apart0) {
  __shared__ float red[WAVES][N];
  int b = blockIdx.x / SLABS, s = blockIdx.x % SLABS;
  int tid = threadIdx.x, w = tid >> 6, l = tid & 63;
  float ca[16];
#pragma unroll
  for (int k = 0; k < 16; ++k) ca[k] = 0.f;
  int i0 = s * RPB + w * RPW;
  for (int t = 0; t < RPW; ++t) {
    size_t rowoff = ((size_t)b * N + (i0 + t)) * N;
    const float* Hrow = H + rowoff;
#pragma unroll
    for (int q = 0; q < 4; ++q) {
      int c0 = q * 256 + l * 4;
      float4 h = *reinterpret_cast<const float4*>(Hrow + c0);
      float e0 = __expf(h.x), e1 = __expf(h.y), e2 = __expf(h.z), e3 = __expf(h.w);
      if constexpr (sizeof(ET) == 2) {
        __half2 p0 = __floats2half2_rn(e0, e1);
        __half2 p1 = __floats2half2_rn(e2, e3);
        uint2 u;
        u.x = *reinterpret_cast<unsigned*>(&p0);
        u.y = *reinterpret_cast<unsigned*>(&p1);
        *reinterpret_cast<uint2*>((__half*)(E + rowoff) + c0) = u;
        float2 r0 = __half22float2(p0), r1 = __half22float2(p1);
        ca[q * 4 + 0] += r0.x; ca[q * 4 + 1] += r0.y;
        ca[q * 4 + 2] += r1.x; ca[q * 4 + 3] += r1.y;
      } else {
        *reinterpret_cast<float4*>((float*)(E + rowoff) + c0) =
            make_float4(e0, e1, e2, e3);
        ca[q * 4 + 0] += e0; ca[q * 4 + 1] += e1;
        ca[q * 4 + 2] += e2; ca[q * 4 + 3] += e3;
      }
    }
  }
#pragma unroll
  for (int q = 0; q < 4; ++q)
    *reinterpret_cast<float4*>(&red[w][q * 256 + l * 4]) =
        make_float4(ca[q * 4], ca[q * 4 + 1], ca[q * 4 + 2], ca[q * 4 + 3]);
  __syncthreads();
  for (int j = tid; j < N; j += TPB) {
    float a = 0.f;
#pragma unroll
    for (int p = 0; p < WAVES; ++p) a += red[p][j];
    Apart0[((size_t)b * SLABS + s) * N + j] = a;
  }
}

template <typename ET, bool FIRST, bool LAST>
__global__ __launch_bounds__(TPB, 4) void k_pass(
    const ET* E, const float* __restrict__ ApartIn, float* __restrict__ ApartOut,
    const float* __restrict__ cIn, float* __restrict__ cOut,
    float* __restrict__ rbuf, float* M) {
  constexpr int CPL = VT<ET>::CPL, ST = VT<ET>::STEPS;
  __shared__ float cs2[N];
  __shared__ float red[WAVES][N];
  __shared__ float rs[RPB];
  int b = blockIdx.x / SLABS, s = blockIdx.x % SLABS;
  int tid = threadIdx.x, w = tid >> 6, l = tid & 63;

  if (tid < RPB)
    rs[tid] = FIRST ? 1.f : rbuf[(size_t)b * N + s * RPB + tid];
  for (int j = tid; j < N; j += TPB) {
    float A = 0.f;
#pragma unroll
    for (int p = 0; p < SLABS; ++p)
      A += ApartIn[((size_t)b * SLABS + p) * N + j];
    float cn;
    if (FIRST) {
      cn = 1.f / (A + EPS);
    } else {
      float cv = cIn[(size_t)b * N + j];
      cn = cv / (cv * A + EPS);
    }
    cs2[j] = cn;
    if (!LAST && s == 0) cOut[(size_t)b * N + j] = cn;
  }
  __syncthreads();

  float creg[ST * CPL];
#pragma unroll
  for (int q = 0; q < ST; ++q)
#pragma unroll
    for (int m = 0; m < CPL; ++m)
      creg[q * CPL + m] = cs2[q * (64 * CPL) + l * CPL + m];

  float ca[ST * CPL];
#pragma unroll
  for (int k = 0; k < ST * CPL; ++k) ca[k] = 0.f;

  int i0 = s * RPB + w * RPW;
#pragma unroll 2
  for (int t = 0; t < RPW; ++t) {
    int i = i0 + t;
    size_t rowoff = ((size_t)b * N + i) * N;
    const ET* Erow = E + rowoff;
    float ev[ST * CPL];
#pragma unroll
    for (int q = 0; q < ST; ++q)
      load16B(Erow + q * (64 * CPL) + l * CPL, &ev[q * CPL]);
    float a0 = 0.f, a1 = 0.f, a2 = 0.f, a3 = 0.f;
#pragma unroll
    for (int k = 0; k < ST * CPL / 4; ++k) {
      a0 = fmaf(ev[k], creg[k], a0);
      a1 = fmaf(ev[k + 4], creg[k + 4], a1);
      a2 = fmaf(ev[k + 8], creg[k + 8], a2);
      a3 = fmaf(ev[k + 12], creg[k + 12], a3);
    }
    float acc = (a0 + a1) + (a2 + a3);
#pragma unroll
    for (int off = 32; off > 0; off >>= 1) acc += __shfl_xor(acc, off, 64);
    float ro = rs[w * RPW + t];
    float rn = ro / (ro * acc + EPS);
    if (LAST) {
      float* Mrow = M + rowoff;
#pragma unroll
      for (int q = 0; q < ST; ++q)
#pragma unroll
        for (int v = 0; v < CPL / 4; ++v) {
          int k = q * CPL + v * 4;
          float4 o = make_float4(ev[k] * rn * creg[k],
                                 ev[k + 1] * rn * creg[k + 1],
                                 ev[k + 2] * rn * creg[k + 2],
                                 ev[k + 3] * rn * creg[k + 3]);
          *reinterpret_cast<float4*>(Mrow + q * (64 * CPL) + l * CPL + v * 4) = o;
        }
    } else {
      if (l == 0) rbuf[(size_t)b * N + i] = rn;
#pragma unroll
      for (int k = 0; k < ST * CPL; ++k) ca[k] = fmaf(ev[k], rn, ca[k]);
    }
  }

  if (!LAST) {
#pragma unroll
    for (int q = 0; q < ST; ++q)
#pragma unroll
      for (int v = 0; v < CPL / 4; ++v) {
        int k = q * CPL + v * 4;
        *reinterpret_cast<float4*>(&red[w][q * (64 * CPL) + l * CPL + v * 4]) =
            make_float4(ca[k], ca[k + 1], ca[k + 2], ca[k + 3]);
      }
    __syncthreads();
    for (int j = tid; j < N; j += TPB) {
      float a = 0.f;
#pragma unroll
      for (int p = 0; p < WAVES; ++p) a += red[p][j];
      ApartOut[((size_t)b * SLABS + s) * N + j] = a;
    }
  }
}

template <typename ET>
static void run(const float* H, ET* E, float* base, float* M, hipStream_t st) {
  float* Ap[2] = {base, base + (size_t)NB * SLABS * N};
  float* c0 = base + 2 * (size_t)NB * SLABS * N;
  float* cb[2] = {c0, c0 + (size_t)NB * N};
  float* r = c0 + 2 * (size_t)NB * N;
  dim3 g(NB * SLABS), blk(TPB);
  k_init<ET><<<g, blk, 0, st>>>(H, E, Ap[0]);
  for (int j = 0; j < NITER; ++j) {
    const float* ApI = Ap[j & 1];
    float* ApO = Ap[(j + 1) & 1];
    const float* cI = cb[j & 1];
    float* cO = cb[(j + 1) & 1];
    if (j == 0)
      k_pass<ET, true, false><<<g, blk, 0, st>>>(E, ApI, ApO, cI, cO, r, M);
    else if (j == NITER - 1)
      k_pass<ET, false, true><<<g, blk, 0, st>>>(E, ApI, ApO, cI, cO, r, M);
    else
      k_pass<ET, false, false><<<g, blk, 0, st>>>(E, ApI, ApO, cI, cO, r, M);
  }
}

extern "C" void kernel_launch(void* const* d_in, const int* in_sizes, int n_in,
                              void* d_out, int out_size, void* d_ws, size_t ws_size,
                              hipStream_t stream) {
  const float* H = (const float*)d_in[0];
  float* M = (float*)d_out;
  const size_t smallFloats = 2 * (size_t)NB * SLABS * N + 3 * (size_t)NB * N;
  const size_t eBytes = (size_t)NB * N * N * sizeof(__half);  // 128 MB
  if (ws_size >= eBytes + smallFloats * sizeof(float)) {
    __half* E = (__half*)d_ws;
    float* base = (float*)((char*)d_ws + eBytes);
    float* Ap0 = base;
    float* Ap1 = base + (size_t)NB * CSLAB * N;
    void* args[5] = {(void*)&H, (void*)&E, (void*)&Ap0, (void*)&Ap1, (void*)&M};
    hipError_t err = hipLaunchCooperativeKernel(
        reinterpret_cast<void*>(&k_res), dim3(CBLK), dim3(512), args, 0, stream);
    if (err != hipSuccess) {
      run<__half>(H, E, base, M, stream);  // proven V5 path
    }
  } else {
    // fallback: fp32 E aliased with the output buffer, scaled in place on pass 20
    run<float>(H, M, (float*)d_ws, M, stream);
  }
}

// Round 7
// 1120.979 us; speedup vs baseline: 3.6926x; 3.6926x over previous
//
#include <hip/hip_runtime.h>
#include <hip/hip_fp16.h>

// Sinkhorn-Knopp, factorized M = diag(r) * exp(H) * diag(c).
// V7 = V5 multi-launch structure + the launch-bounds fix.
// Session finding: hipcc's __launch_bounds__ 2nd arg behaves CUDA-style
// (min BLOCKS/CU): (512,4) capped k_mega/k_res at exactly 64 VGPR (32
// waves/CU), and (512,8) = 64 waves/CU is impossible -> the r3/r4 build
// failures. So V1-V5's k_pass was register-starved: the unroll-2 ev
// buffers never fit, next-row loads couldn't issue until ca-update freed
// ev -> ~1 load in flight/wave -> 2.9 TB/s effective read BW.
// Fix: k_pass at (512,2) (cap 128 VGPR) + explicit 4-row load groups so
// 8 dwordx4 loads are in flight per wave before any consumption.
// E stored fp16 (128 MB); r staged in LDS (V5 fix, keeps row-loop vmem
// stream pure-E).

constexpr int NB    = 64;
constexpr int N     = 1024;
constexpr int SLABS = 16;           // blocks per batch
constexpr int TPB   = 512;          // threads per block (8 waves)
constexpr int WAVES = TPB / 64;     // 8
constexpr int RPB   = N / SLABS;    // 64 rows per block
constexpr int RPW   = RPB / WAVES;  // 8 rows per wave
constexpr int NITER = 20;
constexpr float EPS = 1e-8f;

static_assert(RPW % 4 == 0, "4-row groups");

template <typename ET> struct VT;
template <> struct VT<__half> { static constexpr int CPL = 8, STEPS = 2; };
template <> struct VT<float>  { static constexpr int CPL = 4, STEPS = 4; };

// 16 B load -> CPL floats
__device__ inline void load16B(const __half* p, float* f) {
  uint4 u = *reinterpret_cast<const uint4*>(p);
  float2 t;
  t = __half22float2(*reinterpret_cast<__half2*>(&u.x)); f[0] = t.x; f[1] = t.y;
  t = __half22float2(*reinterpret_cast<__half2*>(&u.y)); f[2] = t.x; f[3] = t.y;
  t = __half22float2(*reinterpret_cast<__half2*>(&u.z)); f[4] = t.x; f[5] = t.y;
  t = __half22float2(*reinterpret_cast<__half2*>(&u.w)); f[6] = t.x; f[7] = t.y;
}
__device__ inline void load16B(const float* p, float* f) {
  float4 v = *reinterpret_cast<const float4*>(p);
  f[0] = v.x; f[1] = v.y; f[2] = v.z; f[3] = v.w;
}

// ---- init: E = exp(H), plus iteration-1 column partials (r = 1) ----
template <typename ET>
__global__ __launch_bounds__(TPB, 4) void k_init(const float* __restrict__ H,
                                                 ET* __restrict__ E,
                                                 float* __restrict__ Apart0) {
  __shared__ float red[WAVES][N];
  int b = blockIdx.x / SLABS, s = blockIdx.x % SLABS;
  int tid = threadIdx.x, w = tid >> 6, l = tid & 63;
  float ca[16];
#pragma unroll
  for (int k = 0; k < 16; ++k) ca[k] = 0.f;
  int i0 = s * RPB + w * RPW;
  for (int t = 0; t < RPW; ++t) {
    size_t rowoff = ((size_t)b * N + (i0 + t)) * N;
    const float* Hrow = H + rowoff;
#pragma unroll
    for (int q = 0; q < 4; ++q) {
      int c0 = q * 256 + l * 4;
      float4 h = *reinterpret_cast<const float4*>(Hrow + c0);
      float e0 = __expf(h.x), e1 = __expf(h.y), e2 = __expf(h.z), e3 = __expf(h.w);
      if constexpr (sizeof(ET) == 2) {
        __half2 p0 = __floats2half2_rn(e0, e1);
        __half2 p1 = __floats2half2_rn(e2, e3);
        uint2 u;
        u.x = *reinterpret_cast<unsigned*>(&p0);
        u.y = *reinterpret_cast<unsigned*>(&p1);
        *reinterpret_cast<uint2*>((__half*)(E + rowoff) + c0) = u;
        // accumulate the ROUNDED values so partials match stored E
        float2 r0 = __half22float2(p0), r1 = __half22float2(p1);
        ca[q * 4 + 0] += r0.x; ca[q * 4 + 1] += r0.y;
        ca[q * 4 + 2] += r1.x; ca[q * 4 + 3] += r1.y;
      } else {
        *reinterpret_cast<float4*>((float*)(E + rowoff) + c0) =
            make_float4(e0, e1, e2, e3);
        ca[q * 4 + 0] += e0; ca[q * 4 + 1] += e1;
        ca[q * 4 + 2] += e2; ca[q * 4 + 3] += e3;
      }
    }
  }
#pragma unroll
  for (int q = 0; q < 4; ++q)
    *reinterpret_cast<float4*>(&red[w][q * 256 + l * 4]) =
        make_float4(ca[q * 4], ca[q * 4 + 1], ca[q * 4 + 2], ca[q * 4 + 3]);
  __syncthreads();
  for (int j = tid; j < N; j += TPB) {
    float a = 0.f;
#pragma unroll
    for (int p = 0; p < WAVES; ++p) a += red[p][j];
    Apart0[((size_t)b * SLABS + s) * N + j] = a;
  }
}

// ---- one Sinkhorn iteration per launch ----
// NOTE: E and M deliberately NOT both __restrict__ — fp32 fallback aliases them.
template <typename ET, bool FIRST, bool LAST>
__global__ __launch_bounds__(TPB, 2) void k_pass(
    const ET* E, const float* __restrict__ ApartIn, float* __restrict__ ApartOut,
    const float* __restrict__ cIn, float* __restrict__ cOut,
    float* __restrict__ rbuf, float* M) {
  constexpr int CPL = VT<ET>::CPL, ST = VT<ET>::STEPS;
  __shared__ float cs[N];
  __shared__ float red[WAVES][N];
  __shared__ float rs[RPB];
  int b = blockIdx.x / SLABS, s = blockIdx.x % SLABS;
  int tid = threadIdx.x, w = tid >> 6, l = tid & 63;

  // phase a: column-scale update from previous pass's partials,
  // plus staging this block's r-slice into LDS (keeps the row loop's
  // vmem stream pure-E).
  if (tid < RPB)
    rs[tid] = FIRST ? 1.f : rbuf[(size_t)b * N + s * RPB + tid];
  for (int j = tid; j < N; j += TPB) {
    float A = 0.f;
#pragma unroll
    for (int p = 0; p < SLABS; ++p)
      A += ApartIn[((size_t)b * SLABS + p) * N + j];
    float cn;
    if (FIRST) {
      cn = 1.f / (A + EPS);
    } else {
      float cv = cIn[(size_t)b * N + j];
      cn = cv / (cv * A + EPS);
    }
    cs[j] = cn;
    if (!LAST && s == 0) cOut[(size_t)b * N + j] = cn;
  }
  __syncthreads();

  float creg[16];
#pragma unroll
  for (int q = 0; q < ST; ++q)
#pragma unroll
    for (int m = 0; m < CPL; ++m)
      creg[q * CPL + m] = cs[q * (64 * CPL) + l * CPL + m];

  float ca[16];
#pragma unroll
  for (int k = 0; k < 16; ++k) ca[k] = 0.f;

  const int i0 = s * RPB + w * RPW;

  // phase b: 4-row groups. All 8 (fp16) vector loads of a group issue
  // before any consumption -> 4 KB in flight per wave. Outer loop NOT
  // unrolled (ev[4][16] must stay 64 regs, not 128).
#pragma unroll 1
  for (int g = 0; g < RPW / 4; ++g) {
    const int ib = i0 + g * 4;
    float ev[4][16];
#pragma unroll
    for (int t = 0; t < 4; ++t) {
      const ET* Erow = E + ((size_t)b * N + ib + t) * (size_t)N;
#pragma unroll
      for (int q = 0; q < ST; ++q)
        load16B(Erow + q * (64 * CPL) + l * CPL, &ev[t][q * CPL]);
    }
    // 4 independent rowsum trees (same reassociation as V5 -> bit-identical)
    float acc[4];
#pragma unroll
    for (int t = 0; t < 4; ++t) {
      float a0 = 0.f, a1 = 0.f, a2 = 0.f, a3 = 0.f;
#pragma unroll
      for (int k = 0; k < 4; ++k) {
        a0 = fmaf(ev[t][k],      creg[k],      a0);
        a1 = fmaf(ev[t][k + 4],  creg[k + 4],  a1);
        a2 = fmaf(ev[t][k + 8],  creg[k + 8],  a2);
        a3 = fmaf(ev[t][k + 12], creg[k + 12], a3);
      }
      acc[t] = (a0 + a1) + (a2 + a3);
    }
    // 4 butterfly chains interleaved -> shuffle latency overlapped
#pragma unroll
    for (int off = 32; off > 0; off >>= 1) {
#pragma unroll
      for (int t = 0; t < 4; ++t) acc[t] += __shfl_xor(acc[t], off, 64);
    }
    float rn[4];
#pragma unroll
    for (int t = 0; t < 4; ++t) {
      float ro = rs[w * RPW + g * 4 + t];
      rn[t] = ro / (ro * acc[t] + EPS);
    }
    if (LAST) {
#pragma unroll
      for (int t = 0; t < 4; ++t) {
        float* Mrow = M + ((size_t)b * N + ib + t) * (size_t)N;
#pragma unroll
        for (int q = 0; q < ST; ++q)
#pragma unroll
          for (int v = 0; v < CPL / 4; ++v) {
            int k = q * CPL + v * 4;
            float4 o = make_float4(ev[t][k] * rn[t] * creg[k],
                                   ev[t][k + 1] * rn[t] * creg[k + 1],
                                   ev[t][k + 2] * rn[t] * creg[k + 2],
                                   ev[t][k + 3] * rn[t] * creg[k + 3]);
            *reinterpret_cast<float4*>(Mrow + q * (64 * CPL) + l * CPL + v * 4) = o;
          }
      }
    } else {
      if (l == 0) {
#pragma unroll
        for (int t = 0; t < 4; ++t) rbuf[(size_t)b * N + ib + t] = rn[t];
      }
      // next iteration's column partials, same row order as V5
#pragma unroll
      for (int t = 0; t < 4; ++t)
#pragma unroll
        for (int k = 0; k < 16; ++k) ca[k] = fmaf(ev[t][k], rn[t], ca[k]);
    }
  }

  if (!LAST) {
#pragma unroll
    for (int q = 0; q < ST; ++q)
#pragma unroll
      for (int v = 0; v < CPL / 4; ++v) {
        int k = q * CPL + v * 4;
        *reinterpret_cast<float4*>(&red[w][q * (64 * CPL) + l * CPL + v * 4]) =
            make_float4(ca[k], ca[k + 1], ca[k + 2], ca[k + 3]);
      }
    __syncthreads();
    for (int j = tid; j < N; j += TPB) {
      float a = 0.f;
#pragma unroll
      for (int p = 0; p < WAVES; ++p) a += red[p][j];
      ApartOut[((size_t)b * SLABS + s) * N + j] = a;
    }
  }
}

template <typename ET>
static void run(const float* H, ET* E, float* base, float* M, hipStream_t st) {
  float* Ap[2] = {base, base + (size_t)NB * SLABS * N};
  float* c0 = base + 2 * (size_t)NB * SLABS * N;
  float* cb[2] = {c0, c0 + (size_t)NB * N};
  float* r = c0 + 2 * (size_t)NB * N;
  dim3 g(NB * SLABS), blk(TPB);
  k_init<ET><<<g, blk, 0, st>>>(H, E, Ap[0]);
  for (int j = 0; j < NITER; ++j) {
    const float* ApI = Ap[j & 1];
    float* ApO = Ap[(j + 1) & 1];
    const float* cI = cb[j & 1];
    float* cO = cb[(j + 1) & 1];
    if (j == 0)
      k_pass<ET, true, false><<<g, blk, 0, st>>>(E, ApI, ApO, cI, cO, r, M);
    else if (j == NITER - 1)
      k_pass<ET, false, true><<<g, blk, 0, st>>>(E, ApI, ApO, cI, cO, r, M);
    else
      k_pass<ET, false, false><<<g, blk, 0, st>>>(E, ApI, ApO, cI, cO, r, M);
  }
}

extern "C" void kernel_launch(void* const* d_in, const int* in_sizes, int n_in,
                              void* d_out, int out_size, void* d_ws, size_t ws_size,
                              hipStream_t stream) {
  const float* H = (const float*)d_in[0];
  float* M = (float*)d_out;
  const size_t smallFloats = 2 * (size_t)NB * SLABS * N + 3 * (size_t)NB * N;
  const size_t eBytes = (size_t)NB * N * N * sizeof(__half);  // 128 MB
  if (ws_size >= eBytes + smallFloats * sizeof(float)) {
    // fast path: fp16 E in workspace
    run<__half>(H, (__half*)d_ws, (float*)((char*)d_ws + eBytes), M, stream);
  } else {
    // fallback: fp32 E aliased with the output buffer, scaled in place on pass 20
    run<float>(H, M, (float*)d_ws, M, stream);
  }
}